// Round 4
// baseline (16485.751 us; speedup 1.0000x reference)
//
#include <hip/hip_runtime.h>
#include <stdint.h>

// Furthest Point Sampling, B=8, N=131072, NPOINT=2048, exact-match vs JAX ref.
// R3: barrier-free rounds. Publish at WAVE granularity (256 slots/batch,
// dense); every wave polls all 256 slots itself (4/lane) and reduces locally.
// No __syncthreads, no LDS, no block-level reduce in the round loop.
// Slot word: [fbits:32 | (131071-idx):17 @bit12 | round-tag:12], relaxed
// agent-scope atomics only (no acquire/release cache maintenance).

#define NB 8
#define NPTS 131072
#define NPOINT 2048
#define KBLK 32                  // blocks per batch
#define BLOCK 512
#define PPT 8                    // NPTS / (KBLK*BLOCK)
#define WPB (BLOCK / 64)         // waves per block = 8
#define NSLOT (KBLK * WPB)       // 256 wave-slots per batch
#define SPL (NSLOT / 64)         // 4 slots per lane when polling

__device__ uint64_t g_part[NB][NSLOT];

static __device__ __forceinline__ uint64_t ld_rlx(uint64_t* p) {
  return __hip_atomic_load(p, __ATOMIC_RELAXED, __HIP_MEMORY_SCOPE_AGENT);
}
static __device__ __forceinline__ void st_rlx(uint64_t* p, uint64_t v) {
  __hip_atomic_store(p, v, __ATOMIC_RELAXED, __HIP_MEMORY_SCOPE_AGENT);
}

static __device__ __forceinline__ uint64_t max64(uint64_t a, uint64_t b) {
  return a > b ? a : b;
}

__global__ __launch_bounds__(BLOCK, 1) void fps_kernel(
    const float* __restrict__ xyz, int* __restrict__ out) {
  const int b = blockIdx.x & (NB - 1);   // batch -> same XCD for all its blocks
  const int k = blockIdx.x >> 3;         // block-within-batch
  const int tid = threadIdx.x;
  const int lane = tid & 63;
  const int wid = tid >> 6;
  const int slot = k * WPB + wid;        // this wave's publish slot

  const float* __restrict__ X = xyz + (size_t)b * 3u * NPTS;
  const float* __restrict__ Y = X + NPTS;
  const float* __restrict__ Z = Y + NPTS;

  const int base = k * (BLOCK * PPT);

  // Resident state: points and min-dists in registers for the whole kernel.
  float px[PPT], py[PPT], pz[PPT], dist[PPT];
#pragma unroll
  for (int j = 0; j < PPT; ++j) {
    int i = base + j * BLOCK + tid;
    px[j] = X[i];
    py[j] = Y[i];
    pz[j] = Z[i];
    dist[j] = 1e10f;
  }

  if (k == 0 && tid == 0) out[b * NPOINT] = 0;  // first sampled index is 0

  int cur = 0;

  for (int r = 1; r < NPOINT; ++r) {
    // coords of last selected point (uniform; same-address load broadcasts)
    const int lu = __builtin_amdgcn_readfirstlane(cur);
    const float qx = X[lu];
    const float qy = Y[lu];
    const float qz = Z[lu];

    // update dists, local packed argmax. Equal-tag words compare correctly
    // as raw uint64; ties -> smaller idx wins (JAX first-index argmax).
    uint64_t pm = 0;
#pragma unroll
    for (int j = 0; j < PPT; ++j) {
      float dx = __fsub_rn(px[j], qx);
      float dy = __fsub_rn(py[j], qy);
      float dz = __fsub_rn(pz[j], qz);
      // exact JAX order: (dx*dx + dy*dy) + dz*dz, no fma contraction
      float d = __fadd_rn(__fadd_rn(__fmul_rn(dx, dx), __fmul_rn(dy, dy)),
                          __fmul_rn(dz, dz));
      float nd = fminf(dist[j], d);
      dist[j] = nd;
      uint32_t idx = (uint32_t)(base + j * BLOCK + tid);
      uint64_t cand = ((uint64_t)__float_as_uint(nd) << 32) |
                      ((uint64_t)(NPTS - 1u - idx) << 12);
      pm = max64(pm, cand);
    }

    // 64-lane wave reduce
#pragma unroll
    for (int off = 32; off; off >>= 1) {
      uint64_t o = (uint64_t)__shfl_xor((unsigned long long)pm, off, 64);
      pm = max64(pm, o);
    }

    // publish this wave's partial (lane 0), tag = round
    if (lane == 0) st_rlx(&g_part[b][slot], pm | (uint64_t)(uint32_t)r);

    // poll all 256 slots of this batch: 4 per lane, parallel loads
    uint64_t* gp = &g_part[b][0];
    uint64_t w0, w1, w2, w3;
    const uint32_t tag = (uint32_t)r;
    for (;;) {
      w0 = ld_rlx(gp + lane);
      w1 = ld_rlx(gp + lane + 64);
      w2 = ld_rlx(gp + lane + 128);
      w3 = ld_rlx(gp + lane + 192);
      uint64_t bad = ((w0 ^ tag) | (w1 ^ tag) | (w2 ^ tag) | (w3 ^ tag)) &
                     0xFFFull;
      if (bad == 0) break;   // per-lane; satisfied lanes park at convergence
    }

    // local 4-way max, then 64-lane reduce -> every wave knows the winner
    uint64_t m = max64(max64(w0, w1), max64(w2, w3));
#pragma unroll
    for (int off = 32; off; off >>= 1) {
      uint64_t o = (uint64_t)__shfl_xor((unsigned long long)m, off, 64);
      m = max64(m, o);
    }

    int widx = (int)(NPTS - 1u - (uint32_t)((m >> 12) & 0x1FFFFu));
    if (k == 0 && tid == 0) out[b * NPOINT + r] = widx;
    cur = widx;
  }
}

extern "C" void kernel_launch(void* const* d_in, const int* in_sizes, int n_in,
                              void* d_out, int out_size, void* d_ws,
                              size_t ws_size, hipStream_t stream) {
  (void)in_sizes; (void)n_in; (void)d_ws; (void)ws_size; (void)out_size;
  const float* xyz = (const float*)d_in[0];
  int* out = (int*)d_out;
  fps_kernel<<<dim3(NB * KBLK), dim3(BLOCK), 0, stream>>>(xyz, out);
}

// Round 6
// 6481.602 us; speedup vs baseline: 2.5435x; 2.5435x over previous
//
#include <hip/hip_runtime.h>
#include <stdint.h>

// Furthest Point Sampling, B=8, N=131072, NPOINT=2048, exact-match vs JAX ref.
// R4: two-tier sync. Blocks of a batch share an XCD (blockIdx%8, round-robin
// dispatch) -> publish/poll partials through that XCD's L2 with volatile
// (sc0, L1-bypass) accesses (~200cy) instead of agent-scope fabric ops
// (~700-900cy). Correctness does NOT depend on placement: every publish also
// release-writes an agent-scope backstop word; pollers merge it in after 16
// failed fast iterations (never triggers when same-XCD holds).
// Parity double-buffer (round r uses buffer r&1) removes the publisher-ahead
// overwrite race: a publisher can lead a laggard poller by at most 1 round
// (it cannot pass round r+1's poll until every wave published r+1), so the
// r-parity buffer is never overwritten before all pollers consumed round r.
// Slot word: [fbits:32 | (131071-idx):17 @bit12 | round-tag:12]; equal-tag
// words compare as raw uint64, ties -> smaller idx (JAX first-index argmax).
// Tag safety across graph replays: a slot's stale tag is from 2+ rounds back
// (or a prior run's 2046/2047), never equal to the current round's tag.

#define NB 8
#define NPTS 131072
#define NPOINT 2048
#define KBLK 32                  // blocks per batch (one XCD's worth of CUs)
#define BLOCK 512
#define PPT 8                    // NPTS / (KBLK*BLOCK)
#define WPB (BLOCK / 64)         // waves per block = 8
#define NSLOT (KBLK * WPB)       // 256 wave-slots per batch, dense 8B
#define FASTK 16                 // fast poll iters before slow-word merge

__device__ uint64_t g_fast[NB][2][NSLOT];   // L2-path (volatile/sc0)
__device__ uint64_t g_slow[NB][2][NSLOT];   // agent-scope backstop

static __device__ __forceinline__ uint64_t ld_slow(uint64_t* p) {
  return __hip_atomic_load(p, __ATOMIC_RELAXED, __HIP_MEMORY_SCOPE_AGENT);
}
static __device__ __forceinline__ void st_slow(uint64_t* p, uint64_t v) {
  __hip_atomic_store(p, v, __ATOMIC_RELAXED, __HIP_MEMORY_SCOPE_AGENT);
}
static __device__ __forceinline__ uint64_t max64(uint64_t a, uint64_t b) {
  return a > b ? a : b;
}

__global__ __launch_bounds__(BLOCK, 1) void fps_kernel(
    const float* __restrict__ xyz, int* __restrict__ out) {
  const int b = blockIdx.x & (NB - 1);   // batch -> one XCD (round-robin)
  const int k = blockIdx.x >> 3;         // block-within-batch
  const int tid = threadIdx.x;
  const int lane = tid & 63;
  const int wid = tid >> 6;
  const int slot = k * WPB + wid;        // this wave's publish slot

  const float* __restrict__ X = xyz + (size_t)b * 3u * NPTS;
  const float* __restrict__ Y = X + NPTS;
  const float* __restrict__ Z = Y + NPTS;

  const int base = k * (BLOCK * PPT);

  // Resident state: points and min-dists in registers for the whole kernel.
  float px[PPT], py[PPT], pz[PPT], dist[PPT];
#pragma unroll
  for (int j = 0; j < PPT; ++j) {
    int i = base + j * BLOCK + tid;
    px[j] = X[i];
    py[j] = Y[i];
    pz[j] = Z[i];
    dist[j] = 1e10f;
  }

  // LDS broadcast word: [widx:17 @bit12 | tag:12]. Init tag=0 (< round 1).
  __shared__ uint32_t sh_bc;
  if (tid == 0) sh_bc = 0;
  __syncthreads();

  if (k == 0 && tid == 0) out[b * NPOINT] = 0;  // first sampled index is 0

  int cur = 0;

  for (int r = 1; r < NPOINT; ++r) {
    // coords of last selected point (uniform -> scalar loads, K$-cached;
    // X is read-only so scalar caching is safe)
    const int lu = __builtin_amdgcn_readfirstlane(cur);
    const float qx = X[lu];
    const float qy = Y[lu];
    const float qz = Z[lu];

    // update dists, local packed argmax
    uint64_t pm = 0;
#pragma unroll
    for (int j = 0; j < PPT; ++j) {
      float dx = __fsub_rn(px[j], qx);
      float dy = __fsub_rn(py[j], qy);
      float dz = __fsub_rn(pz[j], qz);
      // exact JAX order: (dx*dx + dy*dy) + dz*dz, no fma contraction
      float d = __fadd_rn(__fadd_rn(__fmul_rn(dx, dx), __fmul_rn(dy, dy)),
                          __fmul_rn(dz, dz));
      float nd = fminf(dist[j], d);
      dist[j] = nd;
      uint32_t idx = (uint32_t)(base + j * BLOCK + tid);
      uint64_t cand = ((uint64_t)__float_as_uint(nd) << 32) |
                      ((uint64_t)(NPTS - 1u - idx) << 12);
      pm = max64(pm, cand);
    }

    // 64-lane wave reduce
#pragma unroll
    for (int off = 32; off; off >>= 1) {
      uint64_t o = (uint64_t)__shfl_xor((unsigned long long)pm, off, 64);
      pm = max64(pm, o);
    }

    const int par = r & 1;
    const uint64_t tag = (uint64_t)(uint32_t)r;

    // publish this wave's partial: fast (L2/sc0) first, agent backstop second
    if (lane == 0) {
      uint64_t w = pm | tag;
      *(volatile uint64_t*)&g_fast[b][par][slot] = w;   // sc0 store -> L2
      st_slow(&g_slow[b][par][slot], w);                // coherent backstop
    }

    if (wid == 0) {
      // wave 0 polls all 256 slots: 4 dense coalesced volatile loads/lane
      volatile const uint64_t* gp = &g_fast[b][par][0];
      uint64_t* sp = &g_slow[b][par][0];
      uint64_t w0, w1, w2, w3;
      int it = 0;
      for (;;) {
        w0 = gp[lane];
        w1 = gp[lane + 64];
        w2 = gp[lane + 128];
        w3 = gp[lane + 192];
        uint64_t bad =
            ((w0 ^ tag) | (w1 ^ tag) | (w2 ^ tag) | (w3 ^ tag)) & 0xFFFull;
        if (bad == 0) break;   // per-lane; done lanes park at convergence
        if (++it >= FASTK) {   // placement assumption failed: merge backstop
          uint64_t s0 = ld_slow(sp + lane);
          uint64_t s1 = ld_slow(sp + lane + 64);
          uint64_t s2 = ld_slow(sp + lane + 128);
          uint64_t s3 = ld_slow(sp + lane + 192);
          w0 = ((w0 ^ tag) & 0xFFFull) ? s0 : w0;
          w1 = ((w1 ^ tag) & 0xFFFull) ? s1 : w1;
          w2 = ((w2 ^ tag) & 0xFFFull) ? s2 : w2;
          w3 = ((w3 ^ tag) & 0xFFFull) ? s3 : w3;
          bad = ((w0 ^ tag) | (w1 ^ tag) | (w2 ^ tag) | (w3 ^ tag)) & 0xFFFull;
          if (bad == 0) break;
        }
      }

      uint64_t m = max64(max64(w0, w1), max64(w2, w3));
#pragma unroll
      for (int off = 32; off; off >>= 1) {
        uint64_t o = (uint64_t)__shfl_xor((unsigned long long)m, off, 64);
        m = max64(m, o);
      }

      int widx = (int)(NPTS - 1u - (uint32_t)((m >> 12) & 0x1FFFFu));
      if (tid == 0) {
        if (k == 0) out[b * NPOINT + r] = widx;
        // LDS broadcast. Safe single word: wave 0 cannot write round r+1's
        // value until every wave published r+1, which requires them to have
        // consumed round r's broadcast.
        __hip_atomic_store(&sh_bc, ((uint32_t)widx << 12) | (uint32_t)r,
                           __ATOMIC_RELAXED, __HIP_MEMORY_SCOPE_WORKGROUP);
      }
      cur = widx;
    } else {
      // other waves: spin on the LDS broadcast word (cheap, same-address)
      uint32_t w;
      do {
        w = __hip_atomic_load(&sh_bc, __ATOMIC_RELAXED,
                              __HIP_MEMORY_SCOPE_WORKGROUP);
      } while ((w & 0xFFFu) != (uint32_t)r);
      cur = (int)(w >> 12);
    }
  }
}

extern "C" void kernel_launch(void* const* d_in, const int* in_sizes, int n_in,
                              void* d_out, int out_size, void* d_ws,
                              size_t ws_size, hipStream_t stream) {
  (void)in_sizes; (void)n_in; (void)d_ws; (void)ws_size; (void)out_size;
  const float* xyz = (const float*)d_in[0];
  int* out = (int*)d_out;
  fps_kernel<<<dim3(NB * KBLK), dim3(BLOCK), 0, stream>>>(xyz, out);
}

// Round 7
// 5865.680 us; speedup vs baseline: 2.8105x; 1.1050x over previous
//
#include <hip/hip_runtime.h>
#include <stdint.h>

// Furthest Point Sampling, B=8, N=131072, NPOINT=2048, exact-match vs JAX ref.
// R5 = R4 with a LAZY agent-scope backstop (single-variable change).
// R4 post-mortem: WRITE_SIZE 262 MB == unconditional per-wave agent backstop
// stores (256 slots x 8 batches x 64B x 2047 rounds) -> L2->fabric write
// backpressure on the publish path. Fast path (volatile/sc0 via same-XCD L2)
// was confirmed working (FETCH 320->39 MB vs R3).
// R5: publishers write ONLY the fast word normally. Backstop becomes
// timeout-triggered: a poller failing FASTK fast sweeps re-publishes its own
// word agent-scope and merges agent loads; an LDS-spinner failing SPIN_REPUB
// iters re-publishes its wave's word. Wrong XCD placement => every word
// still reaches the coherent point, rounds complete (slow but correct).
// Parity double-buffer (round r uses buffer r&1): publisher can lead a
// laggard by at most 1 round, so round-r words are never overwritten before
// all pollers consume them. Slot word: [fbits:32|(131071-idx):17@12|tag:12];
// equal-tag words compare as raw uint64, ties -> smaller idx (JAX argmax).
// Stale tags (zero-init bss, or prior replay) never falsely match: tags are
// unique per run (1..2047), and cross-replay words are identical anyway
// (inputs restored bit-identically each replay).

#define NB 8
#define NPTS 131072
#define NPOINT 2048
#define KBLK 32                  // blocks per batch (one XCD's worth of CUs)
#define BLOCK 512
#define PPT 8                    // NPTS / (KBLK*BLOCK)
#define WPB (BLOCK / 64)         // waves per block = 8
#define NSLOT (KBLK * WPB)       // 256 wave-slots per batch, dense 8B
#define FASTK 128                // poller fast sweeps before slow-merge mode
#define SPIN_REPUB 2048          // LDS-spin iters before agent re-publish

__device__ uint64_t g_fast[NB][2][NSLOT];   // L2-path (volatile/sc0)
__device__ uint64_t g_slow[NB][2][NSLOT];   // lazy agent-scope backstop

static __device__ __forceinline__ uint64_t ld_slow(uint64_t* p) {
  return __hip_atomic_load(p, __ATOMIC_RELAXED, __HIP_MEMORY_SCOPE_AGENT);
}
static __device__ __forceinline__ void st_slow(uint64_t* p, uint64_t v) {
  __hip_atomic_store(p, v, __ATOMIC_RELAXED, __HIP_MEMORY_SCOPE_AGENT);
}
static __device__ __forceinline__ uint64_t max64(uint64_t a, uint64_t b) {
  return a > b ? a : b;
}

__global__ __launch_bounds__(BLOCK, 1) void fps_kernel(
    const float* __restrict__ xyz, int* __restrict__ out) {
  const int b = blockIdx.x & (NB - 1);   // batch -> one XCD (round-robin)
  const int k = blockIdx.x >> 3;         // block-within-batch
  const int tid = threadIdx.x;
  const int lane = tid & 63;
  const int wid = tid >> 6;
  const int slot = k * WPB + wid;        // this wave's publish slot

  const float* __restrict__ X = xyz + (size_t)b * 3u * NPTS;
  const float* __restrict__ Y = X + NPTS;
  const float* __restrict__ Z = Y + NPTS;

  const int base = k * (BLOCK * PPT);

  // Resident state: points and min-dists in registers for the whole kernel.
  float px[PPT], py[PPT], pz[PPT], dist[PPT];
#pragma unroll
  for (int j = 0; j < PPT; ++j) {
    int i = base + j * BLOCK + tid;
    px[j] = X[i];
    py[j] = Y[i];
    pz[j] = Z[i];
    dist[j] = 1e10f;
  }

  // LDS broadcast word: [widx:17 @bit12 | tag:12]. Init tag=0 (< round 1).
  __shared__ uint32_t sh_bc;
  if (tid == 0) sh_bc = 0;
  __syncthreads();

  if (k == 0 && tid == 0) out[b * NPOINT] = 0;  // first sampled index is 0

  int cur = 0;

  for (int r = 1; r < NPOINT; ++r) {
    // coords of last selected point (uniform -> scalar loads, K$-cached)
    const int lu = __builtin_amdgcn_readfirstlane(cur);
    const float qx = X[lu];
    const float qy = Y[lu];
    const float qz = Z[lu];

    // update dists, local packed argmax
    uint64_t pm = 0;
#pragma unroll
    for (int j = 0; j < PPT; ++j) {
      float dx = __fsub_rn(px[j], qx);
      float dy = __fsub_rn(py[j], qy);
      float dz = __fsub_rn(pz[j], qz);
      // exact JAX order: (dx*dx + dy*dy) + dz*dz, no fma contraction
      float d = __fadd_rn(__fadd_rn(__fmul_rn(dx, dx), __fmul_rn(dy, dy)),
                          __fmul_rn(dz, dz));
      float nd = fminf(dist[j], d);
      dist[j] = nd;
      uint32_t idx = (uint32_t)(base + j * BLOCK + tid);
      uint64_t cand = ((uint64_t)__float_as_uint(nd) << 32) |
                      ((uint64_t)(NPTS - 1u - idx) << 12);
      pm = max64(pm, cand);
    }

    // 64-lane wave reduce
#pragma unroll
    for (int off = 32; off; off >>= 1) {
      uint64_t o = (uint64_t)__shfl_xor((unsigned long long)pm, off, 64);
      pm = max64(pm, o);
    }

    const int par = r & 1;
    const uint64_t tag = (uint64_t)(uint32_t)r;
    const uint64_t myword = pm | tag;

    // publish this wave's partial: fast (L2/sc0) only, in the common case
    if (lane == 0) {
      *(volatile uint64_t*)&g_fast[b][par][slot] = myword;
    }

    if (wid == 0) {
      // wave 0 polls all 256 slots: 4 dense coalesced volatile loads/lane
      volatile const uint64_t* gp = &g_fast[b][par][0];
      uint64_t* sp = &g_slow[b][par][0];
      uint64_t w0, w1, w2, w3;
      int it = 0;
      bool repub = false;
      for (;;) {
        w0 = gp[lane];
        w1 = gp[lane + 64];
        w2 = gp[lane + 128];
        w3 = gp[lane + 192];
        uint64_t bad =
            ((w0 ^ tag) | (w1 ^ tag) | (w2 ^ tag) | (w3 ^ tag)) & 0xFFFull;
        if (bad == 0) break;   // per-lane; done lanes park at convergence
        if (++it >= FASTK) {   // placement assumption failed: slow mode
          if (!repub) {
            if (lane == 0) st_slow(&sp[slot], myword);
            repub = true;
          }
          uint64_t s0 = ld_slow(sp + lane);
          uint64_t s1 = ld_slow(sp + lane + 64);
          uint64_t s2 = ld_slow(sp + lane + 128);
          uint64_t s3 = ld_slow(sp + lane + 192);
          w0 = ((w0 ^ tag) & 0xFFFull) ? s0 : w0;
          w1 = ((w1 ^ tag) & 0xFFFull) ? s1 : w1;
          w2 = ((w2 ^ tag) & 0xFFFull) ? s2 : w2;
          w3 = ((w3 ^ tag) & 0xFFFull) ? s3 : w3;
          bad = ((w0 ^ tag) | (w1 ^ tag) | (w2 ^ tag) | (w3 ^ tag)) & 0xFFFull;
          if (bad == 0) break;
        }
      }

      uint64_t m = max64(max64(w0, w1), max64(w2, w3));
#pragma unroll
      for (int off = 32; off; off >>= 1) {
        uint64_t o = (uint64_t)__shfl_xor((unsigned long long)m, off, 64);
        m = max64(m, o);
      }

      int widx = (int)(NPTS - 1u - (uint32_t)((m >> 12) & 0x1FFFFu));
      if (tid == 0) {
        if (k == 0) out[b * NPOINT + r] = widx;
        // LDS broadcast; single word is safe: wave 0 cannot produce round
        // r+1's broadcast until every wave published r+1, which requires
        // them to have consumed round r's broadcast.
        __hip_atomic_store(&sh_bc, ((uint32_t)widx << 12) | (uint32_t)r,
                           __ATOMIC_RELAXED, __HIP_MEMORY_SCOPE_WORKGROUP);
      }
      cur = widx;
    } else {
      // other waves: spin on the LDS broadcast word; lazy agent re-publish
      // if it takes pathologically long (cross-XCD placement fallback)
      uint32_t w;
      int it = 0;
      bool repub = false;
      for (;;) {
        w = __hip_atomic_load(&sh_bc, __ATOMIC_RELAXED,
                              __HIP_MEMORY_SCOPE_WORKGROUP);
        if ((w & 0xFFFu) == (uint32_t)r) break;
        if (++it >= SPIN_REPUB && !repub) {
          if (lane == 0) st_slow(&g_slow[b][par][slot], myword);
          repub = true;
        }
      }
      cur = (int)(w >> 12);
    }
  }
}

extern "C" void kernel_launch(void* const* d_in, const int* in_sizes, int n_in,
                              void* d_out, int out_size, void* d_ws,
                              size_t ws_size, hipStream_t stream) {
  (void)in_sizes; (void)n_in; (void)d_ws; (void)ws_size; (void)out_size;
  const float* xyz = (const float*)d_in[0];
  int* out = (int*)d_out;
  fps_kernel<<<dim3(NB * KBLK), dim3(BLOCK), 0, stream>>>(xyz, out);
}